// Round 18
// baseline (261.505 us; speedup 1.0000x reference)
//
#include <hip/hip_runtime.h>
#include <hip/hip_bf16.h>
#include <cstdint>
#include <cstddef>

#define D_MODEL 1024
#define HIDDEN 2048
#define E_ROUTED 14
#define E_TOT 16
#define NTOK 2048
#define NASSIGN 4096   // NTOK * TOP_K
#define NROWS 8192     // NASSIGN + 2*NTOK
#define GEMM_NWG 768   // 3 blocks/CU x 256 CU; 96 per XCD

typedef __bf16 bf16x8 __attribute__((ext_vector_type(8)));
typedef float f32x4 __attribute__((ext_vector_type(4)));

static __device__ __forceinline__ unsigned short f2b(float f) {
  unsigned int u = __builtin_bit_cast(unsigned int, f);
  u += 0x7fffu + ((u >> 16) & 1u);   // RNE to bf16 (finite values only)
  return (unsigned short)(u >> 16);
}

static __device__ __forceinline__ float b2f(unsigned short b) {
  unsigned int u = ((unsigned int)b) << 16;
  return __builtin_bit_cast(float, u);
}

// async global->LDS, 16B per lane; LDS dest = wave-uniform base + lane*16
#define ASYNC_COPY16(gptr, lptr)                                                        \
  __builtin_amdgcn_global_load_lds(                                                     \
      (const __attribute__((address_space(1))) unsigned int*)(gptr),                    \
      (__attribute__((address_space(3))) unsigned int*)(lptr), 16, 0, 0)

// ---------------- Router: logits -> softmax -> top2 -> renorm; write xhat bf16
__global__ __launch_bounds__(256) void router_kernel(
    const float* __restrict__ x, const float* __restrict__ rweight,
    int* __restrict__ topi, float* __restrict__ topw,
    unsigned short* __restrict__ xhat) {
  int n = blockIdx.x, tid = threadIdx.x;
  const float4 xv = reinterpret_cast<const float4*>(x + (size_t)n * D_MODEL)[tid];
  float ss = xv.x * xv.x + xv.y * xv.y + xv.z * xv.z + xv.w * xv.w;
  float lg[E_ROUTED];
#pragma unroll
  for (int e = 0; e < E_ROUTED; ++e) lg[e] = 0.f;
  const float xa[4] = {xv.x, xv.y, xv.z, xv.w};
#pragma unroll
  for (int i = 0; i < 4; ++i) {
    const float* rw = rweight + (size_t)(tid * 4 + i) * E_ROUTED;
    float xd = xa[i];
#pragma unroll
    for (int e = 0; e < E_ROUTED; ++e) lg[e] = fmaf(xd, rw[e], lg[e]);
  }
#pragma unroll
  for (int off = 32; off > 0; off >>= 1) {
    ss += __shfl_xor(ss, off);
#pragma unroll
    for (int e = 0; e < E_ROUTED; ++e) lg[e] += __shfl_xor(lg[e], off);
  }
  __shared__ float red[4][16];
  int wid = tid >> 6, lane = tid & 63;
  if (lane == 0) {
    red[wid][0] = ss;
#pragma unroll
    for (int e = 0; e < E_ROUTED; ++e) red[wid][1 + e] = lg[e];
  }
  __syncthreads();
  __shared__ float s_scale;
  if (tid == 0) {
    float fin[15];
    for (int v = 0; v < 15; ++v) fin[v] = red[0][v] + red[1][v] + red[2][v] + red[3][v];
    s_scale = rsqrtf(fin[0] * (1.f / D_MODEL) + 1.1920929e-07f);
    float mx = fin[1];
    for (int e = 1; e < E_ROUTED; ++e) mx = fmaxf(mx, fin[1 + e]);
    float p[E_ROUTED]; float Z = 0.f;
    for (int e = 0; e < E_ROUTED; ++e) { p[e] = __expf(fin[1 + e] - mx); Z += p[e]; }
    int i0 = 0; float v0 = p[0];
    for (int e = 1; e < E_ROUTED; ++e) if (p[e] > v0) { v0 = p[e]; i0 = e; }
    int i1 = (i0 == 0) ? 1 : 0; float v1 = p[i1];
    for (int e = 0; e < E_ROUTED; ++e) if (e != i0 && p[e] > v1) { v1 = p[e]; i1 = e; }
    v0 /= Z; v1 /= Z;
    float inv = 1.f / (v0 + v1 + 1e-9f);
    topi[2 * n] = i0; topi[2 * n + 1] = i1;
    topw[2 * n] = v0 * inv; topw[2 * n + 1] = v1 * inv;
  }
  __syncthreads();
  float sc = s_scale;
  ushort4 hx;
  hx.x = f2b(xv.x * sc); hx.y = f2b(xv.y * sc);
  hx.z = f2b(xv.z * sc); hx.w = f2b(xv.w * sc);
  reinterpret_cast<ushort4*>(xhat + (size_t)n * D_MODEL)[tid] = hx;
}

// ---------------- Count experts -> offsets + cursors + GEMM work plans
__global__ __launch_bounds__(256) void count_kernel(const int* __restrict__ topi,
                                                    int* __restrict__ goff,
                                                    int* __restrict__ cursor,
                                                    int* __restrict__ base1,
                                                    int* __restrict__ base2) {
  __shared__ int cnt[E_ROUTED];
  int tid = threadIdx.x;
  if (tid < E_ROUTED) cnt[tid] = 0;
  __syncthreads();
  for (int i = tid; i < NASSIGN; i += 256) atomicAdd(&cnt[topi[i]], 1);
  __syncthreads();
  if (tid == 0) {
    int acc = 0;
    for (int e = 0; e < E_ROUTED; ++e) { goff[e] = acc; cursor[e] = acc; acc += cnt[e]; }
    goff[E_ROUTED] = acc;   // == NASSIGN
    // work plans: per group mt = ceil(cnt/128); items = mt * (N/128), m-inner
    int b1 = 0, b2 = 0;
    for (int g = 0; g < E_TOT; ++g) {
      base1[g] = b1; base2[g] = b2;
      int c = (g < E_ROUTED) ? cnt[g] : NTOK;
      int mt = (c + 127) >> 7;
      b1 += mt * (HIDDEN / 128);    // G1: 16 n-panels
      b2 += mt * (D_MODEL / 128);   // G2: 8 n-panels
    }
    base1[E_TOT] = b1; base2[E_TOT] = b2;
  }
}

// ---------------- Scatter assignments into per-expert compact rows
__global__ __launch_bounds__(256) void scatter_kernel(
    const int* __restrict__ topi, const float* __restrict__ topw,
    int* __restrict__ cursor, int* __restrict__ row_token,
    float* __restrict__ row_gate, int* __restrict__ token_rows) {
  int i = blockIdx.x * 256 + threadIdx.x;
  if (i >= NASSIGN) return;
  int e = topi[i];
  int pos = atomicAdd(&cursor[e], 1);
  row_token[pos] = i >> 1;
  row_gate[pos] = topw[i];
  token_rows[i] = pos;
}

// ---------------- Transpose + fp32->bf16 convert: W[e][K][N] -> Wt[e][N][K]
// (R2-verified version.) SCALE: fold rms weight (per-k scale) into W1.
template <int K, int N, bool SCALE>
__global__ __launch_bounds__(256) void convT_kernel(
    const float* __restrict__ Wr, const float* __restrict__ Ws,
    const float* __restrict__ RWr, const float* __restrict__ RWs,
    unsigned short* __restrict__ outT) {
  __shared__ float tile[64][65];
  int g = blockIdx.z;
  const float* src = (g < E_ROUTED) ? Wr + (size_t)g * K * N
                                    : Ws + (size_t)(g - E_ROUTED) * K * N;
  const float* rw = nullptr;
  if constexpr (SCALE)
    rw = (g < E_ROUTED) ? RWr + (size_t)g * K : RWs + (size_t)(g - E_ROUTED) * K;
  int k0 = blockIdx.y * 64, nn0 = blockIdx.x * 64;
  int t = threadIdx.x;
  int kk = t >> 4, nc = (t & 15) * 4;
#pragma unroll
  for (int j = 0; j < 4; ++j) {
    int k = kk + j * 16;
    float4 v = *(const float4*)(src + (size_t)(k0 + k) * N + nn0 + nc);
    float s = 1.f;
    if constexpr (SCALE) s = rw[k0 + k];
    tile[k][nc]     = v.x * s;
    tile[k][nc + 1] = v.y * s;
    tile[k][nc + 2] = v.z * s;
    tile[k][nc + 3] = v.w * s;
  }
  __syncthreads();
  int k8 = (t & 7) * 8;
#pragma unroll
  for (int p = 0; p < 2; ++p) {
    int n = (t >> 3) + p * 32;
    uint4 pk;
    pk.x = (unsigned)f2b(tile[k8 + 0][n]) | ((unsigned)f2b(tile[k8 + 1][n]) << 16);
    pk.y = (unsigned)f2b(tile[k8 + 2][n]) | ((unsigned)f2b(tile[k8 + 3][n]) << 16);
    pk.z = (unsigned)f2b(tile[k8 + 4][n]) | ((unsigned)f2b(tile[k8 + 5][n]) << 16);
    pk.w = (unsigned)f2b(tile[k8 + 6][n]) | ((unsigned)f2b(tile[k8 + 7][n]) << 16);
    *(uint4*)(outT + ((size_t)g * N + nn0 + n) * K + k0 + k8) = pk;
  }
}

// ---------------- Grouped GEMM: persistent blocks over globally XCD-chunked
// compact work list (R10/R16-verified skeleton).
// DIRECT_A (G1): A fragments loaded straight global->VGPR (xhat is L2-hot, 4MB)
// — probes whether the ~12 B/cy/CU staging cap is gload_lds-path-specific.
// B staging unchanged: 32/16KB LDS, global_load_lds, both-sides XOR swizzle.
// G1: h[r] = silu(xhat[token] @ W1t[g]^T)   (bf16 out; rms folded into W1t)
// G2: y[r] = (h[r] @ W2t[g]^T) * gate        (bf16 out)
template <bool G1, int KTOT, int NTOT>
__global__ __launch_bounds__(256, 3) void ffn_gemm(
    const int* __restrict__ goff, const int* __restrict__ base,
    const int* __restrict__ row_token, const float* __restrict__ row_gate,
    const unsigned short* __restrict__ Abase,
    const unsigned short* __restrict__ Wt,
    unsigned short* __restrict__ Hout) {
  __shared__ __align__(16) char smem[G1 ? 16 * 1024 : 32 * 1024];
  __shared__ int sbase[E_TOT + 1];
  __shared__ int sgoff[E_ROUTED + 1];

  int tid = threadIdx.x, lane = tid & 63, wid = tid >> 6;
  if (tid <= E_TOT) sbase[tid] = base[tid];
  if (tid >= 32 && tid <= 32 + E_ROUTED) sgoff[tid - 32] = goff[tid - 32];
  __syncthreads();

  int xcd = blockIdx.x & 7, slot = blockIdx.x >> 3;   // 96 slots per XCD
  int total = sbase[E_TOT];
  int chunk = (total + 7) >> 3;
  int cend = min((xcd + 1) * chunk, total);

  int wr = (wid >> 1) * 64, wc = (wid & 1) * 64;
  int lrow = lane >> 3;                 // 0..7
  int swz = lrow << 4;
  int colB = ((lane & 7) << 4) ^ swz;   // pre-swizzled source byte offset in row
  int l15 = lane & 15;
  int kq = (lane >> 4) << 4;            // per-lane 16B k-chunk within 128B row

  for (int c = xcd * chunk + slot; c < cend; c += (GEMM_NWG >> 3)) {
    // ---- decode item c -> (g, nxb, myb)
    int g = 0;
    while (sbase[g + 1] <= c) ++g;
    int grpStart, cnt;
    if (g < E_ROUTED) { grpStart = sgoff[g]; cnt = sgoff[g + 1] - sgoff[g]; }
    else { grpStart = NASSIGN + (g - E_ROUTED) * NTOK; cnt = NTOK; }
    int mtg = (cnt + 127) >> 7;
    int r = c - sbase[g];
    int nxb = r / mtg;
    int myb = r - nxb * mtg;
    int m0 = myb * 128, n0 = nxb * 128;

    // ---- B staging addresses (both variants) + A setup
    char* sA = smem;                 // G2 only
    char* sB = G1 ? smem : smem + 16 * 1024;
    const char* aSrc[4];             // G2: staged A chunks
    const char* aRow[4];             // G1: per-lane direct row base
    const char* bSrc[4];
#pragma unroll
    for (int i = 0; i < 4; ++i) {
      int row = wid * 32 + i * 8 + lrow;
      bSrc[i] = (const char*)(Wt + ((size_t)g * NTOT + n0 + row) * KTOT) + colB;
      if constexpr (!G1) {
        int rIdx = m0 + row; if (rIdx >= cnt) rIdx = cnt - 1;
        aSrc[i] = (const char*)(Abase + (size_t)(grpStart + rIdx) * KTOT) + colB;
      }
    }
    if constexpr (G1) {
#pragma unroll
      for (int m = 0; m < 4; ++m) {
        int rIdx = m0 + wr + m * 16 + l15;
        if (rIdx >= cnt) rIdx = cnt - 1;
        int srcRow = (g < E_ROUTED) ? row_token[grpStart + rIdx] : rIdx;
        aRow[m] = (const char*)(Abase + (size_t)srcRow * KTOT);
      }
    }

    f32x4 acc[4][4];
#pragma unroll
    for (int m = 0; m < 4; ++m)
#pragma unroll
      for (int n = 0; n < 4; ++n)
#pragma unroll
        for (int cc = 0; cc < 4; ++cc) acc[m][n][cc] = 0.f;

    for (int kt = 0; kt < KTOT / 64; ++kt) {
      // ---- stage B tile (and A tile for G2) into LDS
#pragma unroll
      for (int i = 0; i < 4; ++i) ASYNC_COPY16(bSrc[i], sB + wid * 4096 + i * 1024);
#pragma unroll
      for (int i = 0; i < 4; ++i) bSrc[i] += 128;
      bf16x8 afr[2][4];
      if constexpr (G1) {
        // direct A fragment loads (global; same bytes the LDS path delivered)
#pragma unroll
        for (int ks = 0; ks < 2; ++ks)
#pragma unroll
          for (int m = 0; m < 4; ++m)
            afr[ks][m] = *(const bf16x8*)(aRow[m] + kt * 128 + ks * 64 + kq);
      } else {
#pragma unroll
        for (int i = 0; i < 4; ++i) ASYNC_COPY16(aSrc[i], sA + wid * 4096 + i * 1024);
#pragma unroll
        for (int i = 0; i < 4; ++i) aSrc[i] += 128;
      }
      __syncthreads();   // drains vmcnt(0) -> tile (and A frags) ready

      // ---- compute: 2 K=32 steps, 16 MFMA each
#pragma unroll
      for (int ks = 0; ks < 2; ++ks) {
        int kb = ks * 64 + kq;
        bf16x8 af[4], bfr[4];
#pragma unroll
        for (int m = 0; m < 4; ++m) {
          if constexpr (G1) {
            af[m] = afr[ks][m];
          } else {
            int rr = wr + m * 16 + l15;
            af[m] = *(const bf16x8*)(sA + (rr << 7) + (kb ^ ((rr & 7) << 4)));
          }
        }
#pragma unroll
        for (int n = 0; n < 4; ++n) {
          int rr = wc + n * 16 + l15;
          bfr[n] = *(const bf16x8*)(sB + (rr << 7) + (kb ^ ((rr & 7) << 4)));
        }
#pragma unroll
        for (int m = 0; m < 4; ++m)
#pragma unroll
          for (int n = 0; n < 4; ++n)
            acc[m][n] = __builtin_amdgcn_mfma_f32_16x16x32_bf16(af[m], bfr[n], acc[m][n], 0, 0, 0);
      }
      __syncthreads();   // all waves done reading before next stage overwrites
    }

    // ---- epilogue. C/D: col = lane&15, row = (lane>>4)*4 + j  [m89-verified]
    int lr = (lane >> 4) * 4;
#pragma unroll
    for (int m = 0; m < 4; ++m) {
      int rloc = m0 + wr + m * 16 + lr;
#pragma unroll
      for (int j = 0; j < 4; ++j) {
        if (rloc + j < cnt) {
          size_t rg = (size_t)(grpStart + rloc + j);
          if constexpr (G1) {
#pragma unroll
            for (int n = 0; n < 4; ++n) {
              float v = acc[m][n][j];
              float sv = v / (1.f + __expf(-v));
              Hout[rg * HIDDEN + (n0 + wc + n * 16 + l15)] = f2b(sv);
            }
          } else {
            float gate = 1.f;
            if (g < E_ROUTED) gate = row_gate[rg];
#pragma unroll
            for (int n = 0; n < 4; ++n)
              Hout[rg * D_MODEL + (n0 + wc + n * 16 + l15)] = f2b(acc[m][n][j] * gate);
          }
        }
      }
    }
    // next item's STAGE can't race: last k-loop __syncthreads retired all reads,
    // and epilogue touches only registers + global.
  }
}

// ---------------- Combine: out[n] = y[a0] + y[a1] + y[s0+n] + y[s1+n]  (y bf16)
__global__ __launch_bounds__(256) void combine_kernel(
    const unsigned short* __restrict__ y, const int* __restrict__ token_rows,
    float* __restrict__ out) {
  int n = blockIdx.x, tid = threadIdx.x;
  int a0 = token_rows[2 * n], a1 = token_rows[2 * n + 1];
  ushort4 a = reinterpret_cast<const ushort4*>(y + (size_t)a0 * D_MODEL)[tid];
  ushort4 b = reinterpret_cast<const ushort4*>(y + (size_t)a1 * D_MODEL)[tid];
  ushort4 c = reinterpret_cast<const ushort4*>(y + (size_t)(NASSIGN + n) * D_MODEL)[tid];
  ushort4 d = reinterpret_cast<const ushort4*>(y + (size_t)(NASSIGN + NTOK + n) * D_MODEL)[tid];
  float4 r;
  r.x = b2f(a.x) + b2f(b.x) + b2f(c.x) + b2f(d.x);
  r.y = b2f(a.y) + b2f(b.y) + b2f(c.y) + b2f(d.y);
  r.z = b2f(a.z) + b2f(b.z) + b2f(c.z) + b2f(d.z);
  r.w = b2f(a.w) + b2f(b.w) + b2f(c.w) + b2f(d.w);
  reinterpret_cast<float4*>(out + (size_t)n * D_MODEL)[tid] = r;
}

extern "C" void kernel_launch(void* const* d_in, const int* in_sizes, int n_in,
                              void* d_out, int out_size, void* d_ws, size_t ws_size,
                              hipStream_t stream) {
  const float* x        = (const float*)d_in[0];
  const float* router_w = (const float*)d_in[1];
  const float* rms_w    = (const float*)d_in[2];
  const float* w1       = (const float*)d_in[3];
  const float* w2       = (const float*)d_in[4];
  const float* rms_w_s  = (const float*)d_in[5];
  const float* w1_s    = (const float*)d_in[6];
  const float* w2_s    = (const float*)d_in[7];
  float* out = (float*)d_out;

  char* ws = (char*)d_ws;
  unsigned short* xhat = (unsigned short*)ws;                         // 4 MB
  unsigned short* h    = (unsigned short*)(ws + ((size_t)4 << 20));   // 32 MB
  unsigned short* y    = (unsigned short*)(ws + ((size_t)36 << 20));  // 16 MB (bf16)
  unsigned short* w1t  = (unsigned short*)(ws + ((size_t)68 << 20));  // 64 MB [16][H][D]
  unsigned short* w2t  = (unsigned short*)(ws + ((size_t)132 << 20)); // 64 MB [16][D][H]
  char* meta = ws + ((size_t)196 << 20);
  int*   topi       = (int*)(meta);
  float* topw       = (float*)(meta + (16 << 10));
  int*   row_token  = (int*)(meta + (32 << 10));
  float* row_gate   = (float*)(meta + (48 << 10));
  int*   token_rows = (int*)(meta + (64 << 10));
  int*   goff       = (int*)(meta + (80 << 10));          // 17 ints
  int*   cursor     = (int*)(meta + (80 << 10) + 128);    // 14 ints
  int*   base1      = (int*)(meta + (80 << 10) + 256);    // 17 ints
  int*   base2      = (int*)(meta + (80 << 10) + 384);    // 17 ints

  router_kernel<<<NTOK, 256, 0, stream>>>(x, router_w, topi, topw, xhat);
  count_kernel<<<1, 256, 0, stream>>>(topi, goff, cursor, base1, base2);
  scatter_kernel<<<NASSIGN / 256, 256, 0, stream>>>(topi, topw, cursor, row_token,
                                                    row_gate, token_rows);
  convT_kernel<D_MODEL, HIDDEN, true><<<dim3(HIDDEN / 64, D_MODEL / 64, E_TOT), 256, 0, stream>>>(
      w1, w1_s, rms_w, rms_w_s, w1t);
  convT_kernel<HIDDEN, D_MODEL, false><<<dim3(D_MODEL / 64, HIDDEN / 64, E_TOT), 256, 0, stream>>>(
      w2, w2_s, nullptr, nullptr, w2t);
  ffn_gemm<true, D_MODEL, HIDDEN><<<GEMM_NWG, 256, 0, stream>>>(
      goff, base1, row_token, row_gate, xhat, w1t, h);
  ffn_gemm<false, HIDDEN, D_MODEL><<<GEMM_NWG, 256, 0, stream>>>(
      goff, base2, row_token, row_gate, h, w2t, y);
  combine_kernel<<<NTOK, 256, 0, stream>>>(y, token_rows, out);
}

// Round 19
// 226.572 us; speedup vs baseline: 1.1542x; 1.1542x over previous
//
#include <hip/hip_runtime.h>
#include <hip/hip_bf16.h>
#include <cstdint>
#include <cstddef>

#define D_MODEL 1024
#define HIDDEN 2048
#define E_ROUTED 14
#define E_TOT 16
#define NTOK 2048
#define NASSIGN 4096   // NTOK * TOP_K
#define NROWS 8192     // NASSIGN + 2*NTOK
#define GEMM_NWG 768   // 3 blocks/CU x 256 CU; 96 per XCD

typedef __bf16 bf16x8 __attribute__((ext_vector_type(8)));
typedef float f32x4 __attribute__((ext_vector_type(4)));

static __device__ __forceinline__ unsigned short f2b(float f) {
  unsigned int u = __builtin_bit_cast(unsigned int, f);
  u += 0x7fffu + ((u >> 16) & 1u);   // RNE to bf16 (finite values only)
  return (unsigned short)(u >> 16);
}

static __device__ __forceinline__ float b2f(unsigned short b) {
  unsigned int u = ((unsigned int)b) << 16;
  return __builtin_bit_cast(float, u);
}

// async global->LDS, 16B per lane; LDS dest = wave-uniform base + lane*16
#define ASYNC_COPY16(gptr, lptr)                                                        \
  __builtin_amdgcn_global_load_lds(                                                     \
      (const __attribute__((address_space(1))) unsigned int*)(gptr),                    \
      (__attribute__((address_space(3))) unsigned int*)(lptr), 16, 0, 0)

// ---------------- Router: logits -> softmax -> top2 -> renorm; write xhat bf16
__global__ __launch_bounds__(256) void router_kernel(
    const float* __restrict__ x, const float* __restrict__ rweight,
    int* __restrict__ topi, float* __restrict__ topw,
    unsigned short* __restrict__ xhat) {
  int n = blockIdx.x, tid = threadIdx.x;
  const float4 xv = reinterpret_cast<const float4*>(x + (size_t)n * D_MODEL)[tid];
  float ss = xv.x * xv.x + xv.y * xv.y + xv.z * xv.z + xv.w * xv.w;
  float lg[E_ROUTED];
#pragma unroll
  for (int e = 0; e < E_ROUTED; ++e) lg[e] = 0.f;
  const float xa[4] = {xv.x, xv.y, xv.z, xv.w};
#pragma unroll
  for (int i = 0; i < 4; ++i) {
    const float* rw = rweight + (size_t)(tid * 4 + i) * E_ROUTED;
    float xd = xa[i];
#pragma unroll
    for (int e = 0; e < E_ROUTED; ++e) lg[e] = fmaf(xd, rw[e], lg[e]);
  }
#pragma unroll
  for (int off = 32; off > 0; off >>= 1) {
    ss += __shfl_xor(ss, off);
#pragma unroll
    for (int e = 0; e < E_ROUTED; ++e) lg[e] += __shfl_xor(lg[e], off);
  }
  __shared__ float red[4][16];
  int wid = tid >> 6, lane = tid & 63;
  if (lane == 0) {
    red[wid][0] = ss;
#pragma unroll
    for (int e = 0; e < E_ROUTED; ++e) red[wid][1 + e] = lg[e];
  }
  __syncthreads();
  __shared__ float s_scale;
  if (tid == 0) {
    float fin[15];
    for (int v = 0; v < 15; ++v) fin[v] = red[0][v] + red[1][v] + red[2][v] + red[3][v];
    s_scale = rsqrtf(fin[0] * (1.f / D_MODEL) + 1.1920929e-07f);
    float mx = fin[1];
    for (int e = 1; e < E_ROUTED; ++e) mx = fmaxf(mx, fin[1 + e]);
    float p[E_ROUTED]; float Z = 0.f;
    for (int e = 0; e < E_ROUTED; ++e) { p[e] = __expf(fin[1 + e] - mx); Z += p[e]; }
    int i0 = 0; float v0 = p[0];
    for (int e = 1; e < E_ROUTED; ++e) if (p[e] > v0) { v0 = p[e]; i0 = e; }
    int i1 = (i0 == 0) ? 1 : 0; float v1 = p[i1];
    for (int e = 0; e < E_ROUTED; ++e) if (e != i0 && p[e] > v1) { v1 = p[e]; i1 = e; }
    v0 /= Z; v1 /= Z;
    float inv = 1.f / (v0 + v1 + 1e-9f);
    topi[2 * n] = i0; topi[2 * n + 1] = i1;
    topw[2 * n] = v0 * inv; topw[2 * n + 1] = v1 * inv;
  }
  __syncthreads();
  float sc = s_scale;
  ushort4 hx;
  hx.x = f2b(xv.x * sc); hx.y = f2b(xv.y * sc);
  hx.z = f2b(xv.z * sc); hx.w = f2b(xv.w * sc);
  reinterpret_cast<ushort4*>(xhat + (size_t)n * D_MODEL)[tid] = hx;
}

// ---------------- Count experts -> offsets + cursors + GEMM work plans
__global__ __launch_bounds__(256) void count_kernel(const int* __restrict__ topi,
                                                    int* __restrict__ goff,
                                                    int* __restrict__ cursor,
                                                    int* __restrict__ base1,
                                                    int* __restrict__ base2) {
  __shared__ int cnt[E_ROUTED];
  int tid = threadIdx.x;
  if (tid < E_ROUTED) cnt[tid] = 0;
  __syncthreads();
  for (int i = tid; i < NASSIGN; i += 256) atomicAdd(&cnt[topi[i]], 1);
  __syncthreads();
  if (tid == 0) {
    int acc = 0;
    for (int e = 0; e < E_ROUTED; ++e) { goff[e] = acc; cursor[e] = acc; acc += cnt[e]; }
    goff[E_ROUTED] = acc;   // == NASSIGN
    // work plans: per group mt = ceil(cnt/128); items = mt * (N/128), m-inner
    int b1 = 0, b2 = 0;
    for (int g = 0; g < E_TOT; ++g) {
      base1[g] = b1; base2[g] = b2;
      int c = (g < E_ROUTED) ? cnt[g] : NTOK;
      int mt = (c + 127) >> 7;
      b1 += mt * (HIDDEN / 128);    // G1: 16 n-panels
      b2 += mt * (D_MODEL / 128);   // G2: 8 n-panels
    }
    base1[E_TOT] = b1; base2[E_TOT] = b2;
  }
}

// ---------------- Scatter assignments into per-expert compact rows
__global__ __launch_bounds__(256) void scatter_kernel(
    const int* __restrict__ topi, const float* __restrict__ topw,
    int* __restrict__ cursor, int* __restrict__ row_token,
    float* __restrict__ row_gate, int* __restrict__ token_rows) {
  int i = blockIdx.x * 256 + threadIdx.x;
  if (i >= NASSIGN) return;
  int e = topi[i];
  int pos = atomicAdd(&cursor[e], 1);
  row_token[pos] = i >> 1;
  row_gate[pos] = topw[i];
  token_rows[i] = pos;
}

// ---------------- Transpose + fp32->bf16 convert: W[e][K][N] -> Wt[e][N][K]
// (R2-verified version.) SCALE: fold rms weight (per-k scale) into W1.
template <int K, int N, bool SCALE>
__global__ __launch_bounds__(256) void convT_kernel(
    const float* __restrict__ Wr, const float* __restrict__ Ws,
    const float* __restrict__ RWr, const float* __restrict__ RWs,
    unsigned short* __restrict__ outT) {
  __shared__ float tile[64][65];
  int g = blockIdx.z;
  const float* src = (g < E_ROUTED) ? Wr + (size_t)g * K * N
                                    : Ws + (size_t)(g - E_ROUTED) * K * N;
  const float* rw = nullptr;
  if constexpr (SCALE)
    rw = (g < E_ROUTED) ? RWr + (size_t)g * K : RWs + (size_t)(g - E_ROUTED) * K;
  int k0 = blockIdx.y * 64, nn0 = blockIdx.x * 64;
  int t = threadIdx.x;
  int kk = t >> 4, nc = (t & 15) * 4;
#pragma unroll
  for (int j = 0; j < 4; ++j) {
    int k = kk + j * 16;
    float4 v = *(const float4*)(src + (size_t)(k0 + k) * N + nn0 + nc);
    float s = 1.f;
    if constexpr (SCALE) s = rw[k0 + k];
    tile[k][nc]     = v.x * s;
    tile[k][nc + 1] = v.y * s;
    tile[k][nc + 2] = v.z * s;
    tile[k][nc + 3] = v.w * s;
  }
  __syncthreads();
  int k8 = (t & 7) * 8;
#pragma unroll
  for (int p = 0; p < 2; ++p) {
    int n = (t >> 3) + p * 32;
    uint4 pk;
    pk.x = (unsigned)f2b(tile[k8 + 0][n]) | ((unsigned)f2b(tile[k8 + 1][n]) << 16);
    pk.y = (unsigned)f2b(tile[k8 + 2][n]) | ((unsigned)f2b(tile[k8 + 3][n]) << 16);
    pk.z = (unsigned)f2b(tile[k8 + 4][n]) | ((unsigned)f2b(tile[k8 + 5][n]) << 16);
    pk.w = (unsigned)f2b(tile[k8 + 6][n]) | ((unsigned)f2b(tile[k8 + 7][n]) << 16);
    *(uint4*)(outT + ((size_t)g * N + nn0 + n) * K + k0 + k8) = pk;
  }
}

// ---------------- Grouped GEMM: persistent blocks over globally XCD-chunked
// compact work list (R10/R16-verified). 128x128 tile, 4 waves, 32KB LDS single
// buffer, global_load_lds, both-sides XOR swizzle col^=(row&7)<<4.
// G1: h[r] = silu(xhat[token] @ W1t[g]^T)   (bf16 out; rms folded into W1t)
// G2: y[r] = (h[r] @ W2t[g]^T) * gate        (bf16 out)
template <bool G1, int KTOT, int NTOT>
__global__ __launch_bounds__(256, 3) void ffn_gemm(
    const int* __restrict__ goff, const int* __restrict__ base,
    const int* __restrict__ row_token, const float* __restrict__ row_gate,
    const unsigned short* __restrict__ Abase,
    const unsigned short* __restrict__ Wt,
    unsigned short* __restrict__ Hout) {
  __shared__ __align__(16) char smem[32 * 1024];
  __shared__ int sbase[E_TOT + 1];
  __shared__ int sgoff[E_ROUTED + 1];

  int tid = threadIdx.x, lane = tid & 63, wid = tid >> 6;
  if (tid <= E_TOT) sbase[tid] = base[tid];
  if (tid >= 32 && tid <= 32 + E_ROUTED) sgoff[tid - 32] = goff[tid - 32];
  __syncthreads();

  int xcd = blockIdx.x & 7, slot = blockIdx.x >> 3;   // 96 slots per XCD
  int total = sbase[E_TOT];
  int chunk = (total + 7) >> 3;
  int cend = min((xcd + 1) * chunk, total);

  int wr = (wid >> 1) * 64, wc = (wid & 1) * 64;
  int lrow = lane >> 3;                 // 0..7
  int swz = lrow << 4;
  int colB = ((lane & 7) << 4) ^ swz;   // pre-swizzled source byte offset in row
  int l15 = lane & 15;

  for (int c = xcd * chunk + slot; c < cend; c += (GEMM_NWG >> 3)) {
    // ---- decode item c -> (g, nxb, myb)
    int g = 0;
    while (sbase[g + 1] <= c) ++g;
    int grpStart, cnt;
    if (g < E_ROUTED) { grpStart = sgoff[g]; cnt = sgoff[g + 1] - sgoff[g]; }
    else { grpStart = NASSIGN + (g - E_ROUTED) * NTOK; cnt = NTOK; }
    int mtg = (cnt + 127) >> 7;
    int r = c - sbase[g];
    int nxb = r / mtg;
    int myb = r - nxb * mtg;
    int m0 = myb * 128, n0 = nxb * 128;

    // ---- per-item source addresses
    char* sA = smem;
    char* sB = smem + 16 * 1024;
    const char* aSrc[4];
    const char* bSrc[4];
#pragma unroll
    for (int i = 0; i < 4; ++i) {
      int row = wid * 32 + i * 8 + lrow;
      int rIdx = m0 + row; if (rIdx >= cnt) rIdx = cnt - 1;
      int srcRow;
      if constexpr (G1) srcRow = (g < E_ROUTED) ? row_token[grpStart + rIdx] : rIdx;
      else srcRow = grpStart + rIdx;
      aSrc[i] = (const char*)(Abase + (size_t)srcRow * KTOT) + colB;
      bSrc[i] = (const char*)(Wt + ((size_t)g * NTOT + n0 + row) * KTOT) + colB;
    }

    f32x4 acc[4][4];
#pragma unroll
    for (int m = 0; m < 4; ++m)
#pragma unroll
      for (int n = 0; n < 4; ++n)
#pragma unroll
        for (int cc = 0; cc < 4; ++cc) acc[m][n][cc] = 0.f;

    for (int kt = 0; kt < KTOT / 64; ++kt) {
      // ---- stage tile kt async into LDS (linear dest, pre-swizzled source)
#pragma unroll
      for (int i = 0; i < 4; ++i) ASYNC_COPY16(aSrc[i], sA + wid * 4096 + i * 1024);
#pragma unroll
      for (int i = 0; i < 4; ++i) ASYNC_COPY16(bSrc[i], sB + wid * 4096 + i * 1024);
#pragma unroll
      for (int i = 0; i < 4; ++i) { aSrc[i] += 128; bSrc[i] += 128; }
      __syncthreads();   // drains vmcnt(0) -> tile ready

      // ---- compute: 2 K=32 steps, 16 MFMA each
#pragma unroll
      for (int ks = 0; ks < 2; ++ks) {
        int kb = ks * 64 + ((lane >> 4) << 4);
        bf16x8 af[4], bfr[4];
#pragma unroll
        for (int m = 0; m < 4; ++m) {
          int rr = wr + m * 16 + l15;
          af[m] = *(const bf16x8*)(sA + (rr << 7) + (kb ^ ((rr & 7) << 4)));
        }
#pragma unroll
        for (int n = 0; n < 4; ++n) {
          int rr = wc + n * 16 + l15;
          bfr[n] = *(const bf16x8*)(sB + (rr << 7) + (kb ^ ((rr & 7) << 4)));
        }
#pragma unroll
        for (int m = 0; m < 4; ++m)
#pragma unroll
          for (int n = 0; n < 4; ++n)
            acc[m][n] = __builtin_amdgcn_mfma_f32_16x16x32_bf16(af[m], bfr[n], acc[m][n], 0, 0, 0);
      }
      __syncthreads();   // all waves done reading before next stage overwrites
    }

    // ---- epilogue. C/D: col = lane&15, row = (lane>>4)*4 + j  [m89-verified]
    int lr = (lane >> 4) * 4;
#pragma unroll
    for (int m = 0; m < 4; ++m) {
      int rloc = m0 + wr + m * 16 + lr;
#pragma unroll
      for (int j = 0; j < 4; ++j) {
        if (rloc + j < cnt) {
          size_t rg = (size_t)(grpStart + rloc + j);
          if constexpr (G1) {
#pragma unroll
            for (int n = 0; n < 4; ++n) {
              float v = acc[m][n][j];
              float sv = v / (1.f + __expf(-v));
              Hout[rg * HIDDEN + (n0 + wc + n * 16 + l15)] = f2b(sv);
            }
          } else {
            float gate = 1.f;
            if (g < E_ROUTED) gate = row_gate[rg];
#pragma unroll
            for (int n = 0; n < 4; ++n)
              Hout[rg * D_MODEL + (n0 + wc + n * 16 + l15)] = f2b(acc[m][n][j] * gate);
          }
        }
      }
    }
    // next item's STAGE can't race: last k-loop __syncthreads retired all reads,
    // and epilogue touches only registers + global.
  }
}

// ---------------- Combine: out[n] = y[a0] + y[a1] + y[s0+n] + y[s1+n]  (y bf16)
__global__ __launch_bounds__(256) void combine_kernel(
    const unsigned short* __restrict__ y, const int* __restrict__ token_rows,
    float* __restrict__ out) {
  int n = blockIdx.x, tid = threadIdx.x;
  int a0 = token_rows[2 * n], a1 = token_rows[2 * n + 1];
  ushort4 a = reinterpret_cast<const ushort4*>(y + (size_t)a0 * D_MODEL)[tid];
  ushort4 b = reinterpret_cast<const ushort4*>(y + (size_t)a1 * D_MODEL)[tid];
  ushort4 c = reinterpret_cast<const ushort4*>(y + (size_t)(NASSIGN + n) * D_MODEL)[tid];
  ushort4 d = reinterpret_cast<const ushort4*>(y + (size_t)(NASSIGN + NTOK + n) * D_MODEL)[tid];
  float4 r;
  r.x = b2f(a.x) + b2f(b.x) + b2f(c.x) + b2f(d.x);
  r.y = b2f(a.y) + b2f(b.y) + b2f(c.y) + b2f(d.y);
  r.z = b2f(a.z) + b2f(b.z) + b2f(c.z) + b2f(d.z);
  r.w = b2f(a.w) + b2f(b.w) + b2f(c.w) + b2f(d.w);
  reinterpret_cast<float4*>(out + (size_t)n * D_MODEL)[tid] = r;
}

extern "C" void kernel_launch(void* const* d_in, const int* in_sizes, int n_in,
                              void* d_out, int out_size, void* d_ws, size_t ws_size,
                              hipStream_t stream) {
  const float* x        = (const float*)d_in[0];
  const float* router_w = (const float*)d_in[1];
  const float* rms_w    = (const float*)d_in[2];
  const float* w1       = (const float*)d_in[3];
  const float* w2       = (const float*)d_in[4];
  const float* rms_w_s  = (const float*)d_in[5];
  const float* w1_s    = (const float*)d_in[6];
  const float* w2_s    = (const float*)d_in[7];
  float* out = (float*)d_out;

  char* ws = (char*)d_ws;
  unsigned short* xhat = (unsigned short*)ws;                         // 4 MB
  unsigned short* h    = (unsigned short*)(ws + ((size_t)4 << 20));   // 32 MB
  unsigned short* y    = (unsigned short*)(ws + ((size_t)36 << 20));  // 16 MB (bf16)
  unsigned short* w1t  = (unsigned short*)(ws + ((size_t)68 << 20));  // 64 MB [16][H][D]
  unsigned short* w2t  = (unsigned short*)(ws + ((size_t)132 << 20)); // 64 MB [16][D][H]
  char* meta = ws + ((size_t)196 << 20);
  int*   topi       = (int*)(meta);
  float* topw       = (float*)(meta + (16 << 10));
  int*   row_token  = (int*)(meta + (32 << 10));
  float* row_gate   = (float*)(meta + (48 << 10));
  int*   token_rows = (int*)(meta + (64 << 10));
  int*   goff       = (int*)(meta + (80 << 10));          // 17 ints
  int*   cursor     = (int*)(meta + (80 << 10) + 128);    // 14 ints
  int*   base1      = (int*)(meta + (80 << 10) + 256);    // 17 ints
  int*   base2      = (int*)(meta + (80 << 10) + 384);    // 17 ints

  router_kernel<<<NTOK, 256, 0, stream>>>(x, router_w, topi, topw, xhat);
  count_kernel<<<1, 256, 0, stream>>>(topi, goff, cursor, base1, base2);
  scatter_kernel<<<NASSIGN / 256, 256, 0, stream>>>(topi, topw, cursor, row_token,
                                                    row_gate, token_rows);
  convT_kernel<D_MODEL, HIDDEN, true><<<dim3(HIDDEN / 64, D_MODEL / 64, E_TOT), 256, 0, stream>>>(
      w1, w1_s, rms_w, rms_w_s, w1t);
  convT_kernel<HIDDEN, D_MODEL, false><<<dim3(D_MODEL / 64, HIDDEN / 64, E_TOT), 256, 0, stream>>>(
      w2, w2_s, nullptr, nullptr, w2t);
  ffn_gemm<true, D_MODEL, HIDDEN><<<GEMM_NWG, 256, 0, stream>>>(
      goff, base1, row_token, row_gate, xhat, w1t, h);
  ffn_gemm<false, HIDDEN, D_MODEL><<<GEMM_NWG, 256, 0, stream>>>(
      goff, base2, row_token, row_gate, h, w2t, y);
  combine_kernel<<<NTOK, 256, 0, stream>>>(y, token_rows, out);
}